// Round 23
// baseline (267.857 us; speedup 1.0000x reference)
//
#include <hip/hip_runtime.h>

#define NB 256      // batch
#define TT 200      // time steps
#define DD 1250     // input dim
#define H1 100
#define H2 20
#define NO 2

#define WR 112      // padded W rows
#define KPAD 1280   // padded K

#define CH 8        // scan steps per mask chunk
#define NCHK 25     // 200 / 8
#define NLIN 260    // producer k-chunk iterations: 13 units x 20

typedef __attribute__((ext_vector_type(4))) float f32x4;
typedef __attribute__((ext_vector_type(8))) short s16x8;

__device__ __forceinline__ unsigned short f2bf(float f) {
    unsigned u = __builtin_bit_cast(unsigned, f);
    u += 0x7FFFu + ((u >> 16) & 1u);          // round-to-nearest-even
    return (unsigned short)(u >> 16);
}
__device__ __forceinline__ float bf2f(unsigned short s) {
    unsigned u = ((unsigned)s) << 16;
    return __builtin_bit_cast(float, u);
}

// LDS-only barrier (r18-proven): producer/scan global loads stay in flight.
#define STEP_BARRIER() do {                                             \
    asm volatile("s_waitcnt lgkmcnt(0)\n\ts_barrier" ::: "memory");     \
    __builtin_amdgcn_sched_barrier(0);                                  \
} while (0)

// ============ kernel 0: Wih1 fp32 -> bf16 [112][1280] (padded) ===============
__global__ void prep_w(const float* __restrict__ Wih1, unsigned short* __restrict__ w_ws)
{
    const int idx = blockIdx.x * 256 + threadIdx.x;
    if (idx >= WR * KPAD / 4) return;
    const int r  = idx / (KPAD / 4);
    const int k4 = (idx - r * (KPAD / 4)) * 4;
    unsigned short o[4];
    #pragma unroll
    for (int e = 0; e < 4; ++e) {
        const int k = k4 + e;
        o[e] = (r < H1 && k < DD) ? f2bf(Wih1[r * DD + k]) : (unsigned short)0;
    }
    uint2 pk;
    pk.x = (unsigned)o[0] | ((unsigned)o[1] << 16);
    pk.y = (unsigned)o[2] | ((unsigned)o[3] << 16);
    *(uint2*)&w_ws[r * KPAD + k4] = pk;
}

// ============ fused kernel: per-batch producer (MFMA pre1) + r18 scan ========
// Block b owns batch b. Waves 0-4: r18 scan (pre from LDS ring). Wave 5:
// producer — unit = 16 t-rows; per scan step (between barriers) does 2
// k-chunk MFMA iterations; unit u scheduled in window [16(u-2),16(u-2)+16),
// ring-write (f32, no bf16 roundtrip) at window step 10. Ring depth 8:
// chunk c written at step 8c-22/-30, read at 8c, slot freed at 8c-57. x-tile
// LDS is producer-private (single wave -> no barrier needed); W B-frags load
// straight from L2-hot w_ws into regs (no LDS traffic).
#define FMA4(W, PTR) { const float4 hv_ = *(const float4*)(PTR);            \
    a0 = fmaf((W).x, hv_.x, a0); a1 = fmaf((W).y, hv_.y, a1);               \
    a2 = fmaf((W).z, hv_.z, a2); a3 = fmaf((W).w, hv_.w, a3); }

// producer iteration: publish x(LIN) from named regs V0..V3 into x_s[PB],
// prefetch x(LIN+2) into V0..V3, MFMA x_s[PB] x bq (holds W(LIN)), then
// load bq <- W(LIN+1). PB is a literal -> all reg indices compile-time.
#define PITER(LIN, V0, V1, V2, V3, PB) do {                                  \
    _Pragma("unroll")                                                        \
    for (int q = 0; q < 4; ++q) {                                            \
        const int idx = lane + q * 64;                                       \
        const int row = idx >> 4, seg = idx & 15;                            \
        const int sp = seg ^ row;                                            \
        const float4 vv = (q == 0) ? V0 : (q == 1) ? V1 : (q == 2) ? V2 : V3;\
        *(float4*)&x_s[PB][row * 64 + sp * 4] = vv;                          \
    }                                                                        \
    if ((LIN) + 2 < NLIN) xload((LIN) + 2, V0, V1, V2, V3);                  \
    _Pragma("unroll")                                                        \
    for (int s = 0; s < 2; ++s) {                                            \
        const int row_a = lane & 15;                                         \
        const int sb = s * 8 + (lane >> 4) * 2;                              \
        const int sp0 = (sb + 0) ^ row_a;                                    \
        const int sp1 = (sb + 1) ^ row_a;                                    \
        const float4 av0 = *(const float4*)&x_s[PB][row_a * 64 + sp0 * 4];   \
        const float4 av1 = *(const float4*)&x_s[PB][row_a * 64 + sp1 * 4];   \
        const s16x8 af = {                                                   \
            (short)f2bf(av0.x), (short)f2bf(av0.y),                          \
            (short)f2bf(av0.z), (short)f2bf(av0.w),                          \
            (short)f2bf(av1.x), (short)f2bf(av1.y),                          \
            (short)f2bf(av1.z), (short)f2bf(av1.w) };                        \
        _Pragma("unroll")                                                    \
        for (int nt = 0; nt < 7; ++nt)                                       \
            acc[nt] = __builtin_amdgcn_mfma_f32_16x16x32_bf16(               \
                af, bq[s * 7 + nt], acc[nt], 0, 0, 0);                       \
    }                                                                        \
    if ((LIN) + 1 < NLIN) bload((LIN) + 1);                                  \
} while (0)

__launch_bounds__(384, 1)
__global__ void fused_rnn(const float* __restrict__ x,
                          const unsigned short* __restrict__ w_ws,
                          const float* __restrict__ Whh1,
                          const float* __restrict__ bih1,
                          const float* __restrict__ bhh1,
                          const float* __restrict__ Wih2,
                          const float* __restrict__ Whh2,
                          const float* __restrict__ bih2,
                          const float* __restrict__ bhh2,
                          const float* __restrict__ Wfc,
                          const float* __restrict__ bfc,
                          const float* __restrict__ mask1,
                          const float* __restrict__ mask2,
                          float* __restrict__ out)
{
    __shared__ __align__(16) float x_s[2][16 * 64];      //  8 KB (producer)
    __shared__ __align__(16) float pre_ring[8][CH][104]; // 26.6 KB
    __shared__ alignas(16) float h1_s[2][104];           // [100..103] zero pad
    __shared__ alignas(16) float c_s[2][120];            // [o1|h2]
    __shared__ alignas(16) float h2f_s[H2];
    __shared__ alignas(16) float m_lds[2][CH * H1];

    const int tid = threadIdx.x;
    const int b   = blockIdx.x;
    const float* m1b = mask1 + (size_t)b * TT * H1;
    const float* xb  = x + (size_t)b * TT * DD;

    const bool prodw = (tid >= 320);                     // wave 5
    const int lane = tid - 320;

    // ---------------- scan role setup (r18 exact) ----------------
    const int h = tid >> 1;
    const int p = tid & 1;
    const bool l1t = (tid < 200);
    const bool l2t = (tid >= 256 && tid < 256 + 2 * H2); // wave 4
    const int k2 = (tid - 256) >> 1;
    const int p3 = (tid - 256) & 1;

    float4 w00{}, w01{}, w02{}, w03{}, w04{}, w05{}, w06{}, w07{},
           w08{}, w09{}, w10{}, w11{}, w12{}, w13{}, w14{};
    float b1 = 0.f, b2 = 0.f;

    if (l1t) {
        const float* wr = Whh1 + h * H1 + p * 52;
        w00 = *(const float4*)(wr +  0); w01 = *(const float4*)(wr +  4);
        w02 = *(const float4*)(wr +  8); w03 = *(const float4*)(wr + 12);
        w04 = *(const float4*)(wr + 16); w05 = *(const float4*)(wr + 20);
        w06 = *(const float4*)(wr + 24); w07 = *(const float4*)(wr + 28);
        w08 = *(const float4*)(wr + 32); w09 = *(const float4*)(wr + 36);
        w10 = *(const float4*)(wr + 40); w11 = *(const float4*)(wr + 44);
        if (p == 0) { w12 = *(const float4*)(wr + 48); b1 = bih1[h] + bhh1[h]; }
    } else if (l2t) {
        if (p3 == 0) {
            const float* wr = Wih2 + k2 * H1;            // [0..59]
            w00 = *(const float4*)(wr +  0); w01 = *(const float4*)(wr +  4);
            w02 = *(const float4*)(wr +  8); w03 = *(const float4*)(wr + 12);
            w04 = *(const float4*)(wr + 16); w05 = *(const float4*)(wr + 20);
            w06 = *(const float4*)(wr + 24); w07 = *(const float4*)(wr + 28);
            w08 = *(const float4*)(wr + 32); w09 = *(const float4*)(wr + 36);
            w10 = *(const float4*)(wr + 40); w11 = *(const float4*)(wr + 44);
            w12 = *(const float4*)(wr + 48); w13 = *(const float4*)(wr + 52);
            w14 = *(const float4*)(wr + 56);
            b2 = bih2[k2] + bhh2[k2];
        } else {
            const float* wr = Wih2 + k2 * H1 + 60;       // [60..99]
            w00 = *(const float4*)(wr +  0); w01 = *(const float4*)(wr +  4);
            w02 = *(const float4*)(wr +  8); w03 = *(const float4*)(wr + 12);
            w04 = *(const float4*)(wr + 16); w05 = *(const float4*)(wr + 20);
            w06 = *(const float4*)(wr + 24); w07 = *(const float4*)(wr + 28);
            w08 = *(const float4*)(wr + 32); w09 = *(const float4*)(wr + 36);
            const float* wh = Whh2 + k2 * H2;            // h2 part
            w10 = *(const float4*)(wh +  0); w11 = *(const float4*)(wh +  4);
            w12 = *(const float4*)(wh +  8); w13 = *(const float4*)(wh + 12);
            w14 = *(const float4*)(wh + 16);
        }
    }

    // ---------------- producer setup ----------------
    f32x4 acc[7];
    #pragma unroll
    for (int i = 0; i < 7; ++i)
        #pragma unroll
        for (int c = 0; c < 4; ++c) acc[i][c] = 0.f;
    s16x8 bq[14];
    #pragma unroll
    for (int i = 0; i < 14; ++i) bq[i] = s16x8{};
    float4 xa0{}, xa1{}, xa2{}, xa3{}, xb0{}, xb1{}, xb2{}, xb3{};

    auto xload = [&](int l2, float4& v0, float4& v1, float4& v2, float4& v3) {
        const int un = l2 / 20;
        const int kk = l2 - un * 20;
        const int k0 = kk * 64, t0 = un * 16;
        #pragma unroll
        for (int q = 0; q < 4; ++q) {
            const int idx = lane + q * 64;
            const int row = idx >> 4, seg = idx & 15;
            int t = t0 + row; if (t > TT - 1) t = TT - 1;
            const int gk = k0 + seg * 4;
            const float* xp = xb + (size_t)t * DD + gk;
            float4 v;
            if (gk + 4 <= DD) {
                v = *(const float4*)xp;
            } else {
                v.x = (gk + 0 < DD) ? xp[0] : 0.f;
                v.y = (gk + 1 < DD) ? xp[1] : 0.f;
                v.z = (gk + 2 < DD) ? xp[2] : 0.f;
                v.w = (gk + 3 < DD) ? xp[3] : 0.f;
            }
            if (q == 0) v0 = v; else if (q == 1) v1 = v;
            else if (q == 2) v2 = v; else v3 = v;
        }
    };
    auto bload = [&](int l1i) {
        const int un = l1i / 20;
        const int kk = l1i - un * 20;
        const int k0 = kk * 64;
        #pragma unroll
        for (int s = 0; s < 2; ++s)
            #pragma unroll
            for (int nt = 0; nt < 7; ++nt)
                bq[s * 7 + nt] = *(const s16x8*)&w_ws[
                    (size_t)(nt * 16 + (lane & 15)) * KPAD + k0 + s * 32 + (lane >> 4) * 8];
    };
    auto ringw = [&](int un) {                  // write unit's 16 rows -> ring
        #pragma unroll
        for (int nt = 0; nt < 7; ++nt) {
            const int hh = nt * 16 + (lane & 15);
            #pragma unroll
            for (int r = 0; r < 4; ++r) {
                const int r4 = ((lane >> 4) << 2) + r;
                const int chunk = un * 2 + (r4 >> 3);
                if (hh < H1 && chunk <= 24)
                    pre_ring[chunk & 7][r4 & 7][hh] = acc[nt][r];
            }
        }
        #pragma unroll
        for (int i = 0; i < 7; ++i)
            #pragma unroll
            for (int c = 0; c < 4; ++c) acc[i][c] = 0.f;
    };

    // ---------------- init + prologue ----------------
    for (int i = tid; i < 104; i += 384) { h1_s[0][i] = 0.f; h1_s[1][i] = 0.f; }
    for (int i = tid; i < 120; i += 384) { c_s[0][i] = 0.f; c_s[1][i] = 0.f; }
    if (tid < 200) {                            // mask chunk 0
        const float4 mv = *(const float4*)&m1b[tid * 4];
        *(float4*)&m_lds[0][tid * 4] = mv;
    }
    if (prodw) {                                // units 0,1 (chunks 0-3) solo
        xload(0, xa0, xa1, xa2, xa3);
        xload(1, xb0, xb1, xb2, xb3);
        bload(0);
        for (int u = 0; u < 2; ++u) {
            for (int jj = 0; jj < 10; ++jj) {
                PITER(u * 20 + 2 * jj,     xa0, xa1, xa2, xa3, 0);
                PITER(u * 20 + 2 * jj + 1, xb0, xb1, xb2, xb3, 1);
            }
            ringw(u);
        }
    }
    __syncthreads();                            // ring chunks 0-3 + mask0 live

    // ---------------- main loop ----------------
    int buf = 0;
    for (int c = 0; c < NCHK; ++c) {
        const bool more = (c + 1 < NCHK);
        float4 mst{};

        #pragma unroll
        for (int u = 0; u < CH; ++u) {
            const int t = c * CH + u;
            const int cur = t & 1, nxt = cur ^ 1;

            if (u > 0) STEP_BARRIER();

            if (u == 0 && more && tid < 200)    // mask for chunk c+1
                mst = *(const float4*)&m1b[(c + 1) * (CH * H1) + tid * 4];

            if (prodw) {                        // producer step (window-gated)
                const int s = c * 8 + u;
                if (s < 176) {
                    const int un = 2 + (s >> 4);
                    const int j = s & 15;
                    if (j < 10) {
                        PITER(un * 20 + 2 * j,     xa0, xa1, xa2, xa3, 0);
                        PITER(un * 20 + 2 * j + 1, xb0, xb1, xb2, xb3, 1);
                    } else if (j == 10) {
                        ringw(un);
                    }
                }
            }

            if (l1t) {
                float a0 = (p == 0) ? (pre_ring[c & 7][u][h] + b1) : 0.f;
                const float mv = (p == 1) ? m_lds[buf][u * H1 + h] : 0.f;
                float a1 = 0.f, a2 = 0.f, a3 = 0.f;
                const float* hb = &h1_s[cur][p * 52];
                FMA4(w00, hb +  0); FMA4(w01, hb +  4); FMA4(w02, hb +  8);
                FMA4(w03, hb + 12); FMA4(w04, hb + 16); FMA4(w05, hb + 20);
                FMA4(w06, hb + 24); FMA4(w07, hb + 28); FMA4(w08, hb + 32);
                FMA4(w09, hb + 36); FMA4(w10, hb + 40); FMA4(w11, hb + 44);
                FMA4(w12, hb + 48);
                float part = (a0 + a1) + (a2 + a3);
                float tot  = part + __shfl_xor(part, 1);
                tot = fmaxf(tot, 0.f);                       // h1(t)
                if (p == 0) h1_s[nxt][h] = tot;
                else        c_s[nxt][h] = tot * mv;          // o1(t)
            }

            if (l2t && t >= 1) {
                float a0 = (p3 == 0) ? b2 : 0.f;
                float a1 = 0.f, a2 = 0.f, a3 = 0.f;
                const float* cb = &c_s[cur][p3 * 60];
                FMA4(w00, cb +  0); FMA4(w01, cb +  4); FMA4(w02, cb +  8);
                FMA4(w03, cb + 12); FMA4(w04, cb + 16); FMA4(w05, cb + 20);
                FMA4(w06, cb + 24); FMA4(w07, cb + 28); FMA4(w08, cb + 32);
                FMA4(w09, cb + 36); FMA4(w10, cb + 40); FMA4(w11, cb + 44);
                FMA4(w12, cb + 48); FMA4(w13, cb + 52); FMA4(w14, cb + 56);
                float part = (a0 + a1) + (a2 + a3);
                part += __shfl_xor(part, 1);
                const float h2v = fmaxf(part, 0.f);          // h2(t-1)
                if (p3 == 0) c_s[nxt][100 + k2] = h2v;
            }
        }

        if (more && tid < 200)
            *(float4*)&m_lds[buf ^ 1][tid * 4] = mst;
        if (more) buf ^= 1;
        STEP_BARRIER();                         // chunk boundary (LDS publish)
    }

    // epilogue t = TT: layer2 computes h2(199) from o1(199), h2(198)
    {
        const int cur = TT & 1;                              // 0
        if (l2t) {
            float a0 = (p3 == 0) ? b2 : 0.f;
            float a1 = 0.f, a2 = 0.f, a3 = 0.f;
            const float* cb = &c_s[cur][p3 * 60];
            FMA4(w00, cb +  0); FMA4(w01, cb +  4); FMA4(w02, cb +  8);
            FMA4(w03, cb + 12); FMA4(w04, cb + 16); FMA4(w05, cb + 20);
            FMA4(w06, cb + 24); FMA4(w07, cb + 28); FMA4(w08, cb + 32);
            FMA4(w09, cb + 36); FMA4(w10, cb + 40); FMA4(w11, cb + 44);
            FMA4(w12, cb + 48); FMA4(w13, cb + 52); FMA4(w14, cb + 56);
            float part = (a0 + a1) + (a2 + a3);
            part += __shfl_xor(part, 1);
            if (p3 == 0) h2f_s[k2] = fmaxf(part, 0.f);       // h2(199)
        }
        __syncthreads();
    }

    if (tid < NO) {
        const float* m2 = mask2 + ((size_t)b * TT + (TT - 1)) * H2;
        float s = bfc[tid];
        #pragma unroll
        for (int k = 0; k < H2; ++k)
            s = fmaf(Wfc[tid * H2 + k], h2f_s[k] * m2[k], s);
        out[b * NO + tid] = s;
    }
}

extern "C" void kernel_launch(void* const* d_in, const int* in_sizes, int n_in,
                              void* d_out, int out_size, void* d_ws, size_t ws_size,
                              hipStream_t stream) {
    const float* x     = (const float*)d_in[0];
    const float* Wih1  = (const float*)d_in[1];
    const float* Whh1  = (const float*)d_in[2];
    const float* bih1  = (const float*)d_in[3];
    const float* bhh1  = (const float*)d_in[4];
    const float* Wih2  = (const float*)d_in[5];
    const float* Whh2  = (const float*)d_in[6];
    const float* bih2  = (const float*)d_in[7];
    const float* bhh2  = (const float*)d_in[8];
    const float* Wfc   = (const float*)d_in[9];
    const float* bfc   = (const float*)d_in[10];
    const float* mask1 = (const float*)d_in[11];
    const float* mask2 = (const float*)d_in[12];
    float* out = (float*)d_out;

    unsigned short* w_ws = (unsigned short*)d_ws;            // 286,720 B

    prep_w<<<dim3((WR * KPAD / 4 + 255) / 256), dim3(256), 0, stream>>>(Wih1, w_ws);
    fused_rnn<<<dim3(NB), dim3(384), 0, stream>>>(x, w_ws, Whh1, bih1, bhh1,
                                                  Wih2, Whh2, bih2, bhh2,
                                                  Wfc, bfc, mask1, mask2, out);
}

// Round 24
// 169.058 us; speedup vs baseline: 1.5844x; 1.5844x over previous
//
#include <hip/hip_runtime.h>

#define NB 256      // batch
#define TT 200      // time steps
#define DD 1250     // input dim
#define H1 100
#define H2 20
#define NO 2

// ---- GEMM kernel geometry ----
#define BM 64
#define GRID_A (51200 / BM)   // 800
#define KC 64
#define NCH 20                // 1280 / 64
#define WR 112
#define KPAD 1280

// ---- scan geometry ----
#define CH 8                  // steps per staged chunk
#define NCHK 25               // 200 / 8

typedef __attribute__((ext_vector_type(4))) float f32x4;
typedef __attribute__((ext_vector_type(8))) short s16x8;

__device__ __forceinline__ unsigned short f2bf(float f) {
    unsigned u = __builtin_bit_cast(unsigned, f);
    u += 0x7FFFu + ((u >> 16) & 1u);          // round-to-nearest-even
    return (unsigned short)(u >> 16);
}
__device__ __forceinline__ float bf2f(unsigned short s) {
    unsigned u = ((unsigned)s) << 16;
    return __builtin_bit_cast(float, u);
}

#define GLL(srcp, dstp) __builtin_amdgcn_global_load_lds( \
    (const __attribute__((address_space(1))) void*)(srcp), \
    (__attribute__((address_space(3))) void*)(dstp), 16, 0, 0)

// LDS-only barrier: global loads stay in flight across steps (r18-proven).
#define STEP_BARRIER() do {                                             \
    asm volatile("s_waitcnt lgkmcnt(0)\n\ts_barrier" ::: "memory");     \
    __builtin_amdgcn_sched_barrier(0);                                  \
} while (0)

// ============ kernel 0: Wih1 fp32 -> bf16 [112][1280] (padded) ===============
__global__ void prep_w(const float* __restrict__ Wih1, unsigned short* __restrict__ w_ws)
{
    const int idx = blockIdx.x * 256 + threadIdx.x;
    if (idx >= WR * KPAD / 4) return;
    const int r  = idx / (KPAD / 4);
    const int k4 = (idx - r * (KPAD / 4)) * 4;
    unsigned short o[4];
    #pragma unroll
    for (int e = 0; e < 4; ++e) {
        const int k = k4 + e;
        o[e] = (r < H1 && k < DD) ? f2bf(Wih1[r * DD + k]) : (unsigned short)0;
    }
    uint2 pk;
    pk.x = (unsigned)o[0] | ((unsigned)o[1] << 16);
    pk.y = (unsigned)o[2] | ((unsigned)o[3] << 16);
    *(uint2*)&w_ws[r * KPAD + k4] = pk;
}

// ============ kernel 1: pre1[(b*TT+t)*H1 + h] (bf16) — r16-exact =============
// async DMA staging (global_load_lds w=16) + pre-swizzled source / swizzled
// read; double-buffered; one __syncthreads per chunk. ~60us (TLP-saturated;
// r22's deeper pipeline was neutral).
__launch_bounds__(256, 4)
__global__ void gemm_pre(const float* __restrict__ x,
                         const unsigned short* __restrict__ w_ws,
                         unsigned short* __restrict__ preT)
{
    __shared__ __align__(16) float          a_sf[2][BM * 64];   // 32768 B
    __shared__ __align__(16) unsigned short w_sh[2][WR * 64];   // 28672 B

    const int tid = threadIdx.x;
    const int bid = blockIdx.x;
    const int wv  = tid >> 6;
    const int ln  = tid & 63;
    const int c16 = ln & 15;
    const int kgrp = ln >> 4;

    f32x4 acc[7];
    #pragma unroll
    for (int i = 0; i < 7; ++i)
        #pragma unroll
        for (int c = 0; c < 4; ++c) acc[i][c] = 0.f;

    auto agll = [&](int k0, int buf) {
        #pragma unroll
        for (int q = 0; q < 4; ++q) {
            const int idx  = tid + q * 256;
            const int row  = idx >> 4;
            const int segp = idx & 15;
            const int segl = segp ^ (row & 15);            // inverse swizzle
            const float* src = x + (size_t)(bid * BM + row) * DD + k0 + segl * 4;
            GLL(src, &a_sf[buf][idx * 4]);
        }
    };
    auto wgll = [&](int k0, int buf) {
        #pragma unroll
        for (int q = 0; q < 4; ++q) {
            const int idx = tid + q * 256;
            if (idx < WR * 8) {
                const int row = idx >> 3;
                const int c8p = idx & 7;
                const int c8l = c8p ^ (row & 7);           // inverse swizzle
                const unsigned short* src = w_ws + row * KPAD + k0 + c8l * 8;
                GLL(src, &w_sh[buf][idx * 8]);
            }
        }
    };

    auto mfma_chunk = [&](int buf) {
        #pragma unroll
        for (int s = 0; s < 2; ++s) {
            const int row_a = wv * 16 + c16;
            const int sb = s * 8 + kgrp * 2;
            const int sp0 = (sb + 0) ^ (row_a & 15);
            const int sp1 = (sb + 1) ^ (row_a & 15);
            const float4 av0 = *(const float4*)&a_sf[buf][row_a * 64 + sp0 * 4];
            const float4 av1 = *(const float4*)&a_sf[buf][row_a * 64 + sp1 * 4];
            const s16x8 af = {
                (short)f2bf(av0.x), (short)f2bf(av0.y),
                (short)f2bf(av0.z), (short)f2bf(av0.w),
                (short)f2bf(av1.x), (short)f2bf(av1.y),
                (short)f2bf(av1.z), (short)f2bf(av1.w) };
            #pragma unroll
            for (int nt = 0; nt < 7; ++nt) {
                const int row_b = nt * 16 + c16;
                const int c8  = s * 4 + kgrp;
                const int c8p = c8 ^ (row_b & 7);
                const s16x8 bf = *(const s16x8*)&w_sh[buf][row_b * 64 + c8p * 8];
                acc[nt] = __builtin_amdgcn_mfma_f32_16x16x32_bf16(af, bf, acc[nt], 0, 0, 0);
            }
        }
    };

    // tail chunk 19 (k 1216..1279, valid < 1250): guarded register loads
    float4 ta[4];
    #pragma unroll
    for (int q = 0; q < 4; ++q) {
        const int idx  = tid + q * 256;
        const int row  = idx >> 4;
        const int segl = idx & 15;
        const int gk   = 19 * KC + segl * 4;
        const float* xp = x + (size_t)(bid * BM + row) * DD + gk;
        float4 v;
        v.x = (gk + 0 < DD) ? xp[0] : 0.f;
        v.y = (gk + 1 < DD) ? xp[1] : 0.f;
        v.z = (gk + 2 < DD) ? xp[2] : 0.f;
        v.w = (gk + 3 < DD) ? xp[3] : 0.f;
        ta[q] = v;
    }

    agll(0, 0);
    wgll(0, 0);

    for (int kc = 0; kc < 19; ++kc) {
        const int buf = kc & 1;
        __syncthreads();                      // chunk kc resident in LDS[buf]
        if (kc + 1 < 19) agll((kc + 1) * KC, buf ^ 1);
        wgll((kc + 1) * KC, buf ^ 1);         // kc+1 == 19 ok (W padded)
        mfma_chunk(buf);
    }

    // tail: A via swizzled ds_write into buf 1
    #pragma unroll
    for (int q = 0; q < 4; ++q) {
        const int idx  = tid + q * 256;
        const int row  = idx >> 4;
        const int segl = idx & 15;
        const int sp   = segl ^ (row & 15);
        *(float4*)&a_sf[1][row * 64 + sp * 4] = ta[q];
    }
    __syncthreads();                          // publishes A-tail + W chunk 19
    mfma_chunk(1);

    // C/D layout: col = l&15, row = (l>>4)*4 + reg  (m89-verified)
    const int rg = bid * BM + wv * 16 + (kgrp << 2);
    #pragma unroll
    for (int nt = 0; nt < 7; ++nt) {
        const int col = nt * 16 + c16;
        if (col < H1) {
            #pragma unroll
            for (int r = 0; r < 4; ++r)
                preT[(size_t)(rg + r) * H1 + col] = f2bf(acc[nt][r]);
        }
    }
}

// ============ kernel 2: fused two-layer scan + FC (r18 exact, proven) ========
// Per-step: 2-lane-split dots (f32 weights in named regs), shfl reduce,
// chunked double-buffered staging of pre/mask, LDS-only in-chunk barriers.
// ~105us = 200 x ~1260cy; bracketed as structural floor by 7 variants.
#define FMA4(W, PTR) { const float4 hv_ = *(const float4*)(PTR);            \
    a0 = fmaf((W).x, hv_.x, a0); a1 = fmaf((W).y, hv_.y, a1);               \
    a2 = fmaf((W).z, hv_.z, a2); a3 = fmaf((W).w, hv_.w, a3); }

__launch_bounds__(320, 1)
__global__ void scan_rnn(const unsigned short* __restrict__ preT,
                         const float* __restrict__ Whh1,
                         const float* __restrict__ bih1,
                         const float* __restrict__ bhh1,
                         const float* __restrict__ Wih2,
                         const float* __restrict__ Whh2,
                         const float* __restrict__ bih2,
                         const float* __restrict__ bhh2,
                         const float* __restrict__ Wfc,
                         const float* __restrict__ bfc,
                         const float* __restrict__ mask1,
                         const float* __restrict__ mask2,
                         float* __restrict__ out)
{
    __shared__ alignas(16) float h1_s[2][104];    // [100..103] zero pad
    __shared__ alignas(16) float c_s[2][120];     // [0..99]=o1, [100..119]=h2
    __shared__ alignas(16) float h2f_s[H2];
    __shared__ alignas(16) float m_lds[2][CH * H1];   // mask1 chunks (f32)
    __shared__ alignas(16) float p_lds[2][CH * H1];   // pre1 chunks (f32)

    const int tid = threadIdx.x;
    const int b   = blockIdx.x;
    const float* m1b = mask1 + (size_t)b * TT * H1;
    const unsigned short* pTb = preT + (size_t)b * TT * H1;   // row-major [t][h]

    const int h = tid >> 1;
    const int p = tid & 1;
    const bool l1t = (tid < 200);
    const bool l2t = (tid >= 256 && tid < 256 + 2 * H2);   // wave 4 only
    const int k2 = (tid - 256) >> 1;
    const int p3 = (tid - 256) & 1;

    float4 w00{}, w01{}, w02{}, w03{}, w04{}, w05{}, w06{}, w07{},
           w08{}, w09{}, w10{}, w11{}, w12{}, w13{}, w14{};
    float b1 = 0.f, b2 = 0.f;

    if (l1t) {
        const float* wr = Whh1 + h * H1 + p * 52;
        w00 = *(const float4*)(wr +  0); w01 = *(const float4*)(wr +  4);
        w02 = *(const float4*)(wr +  8); w03 = *(const float4*)(wr + 12);
        w04 = *(const float4*)(wr + 16); w05 = *(const float4*)(wr + 20);
        w06 = *(const float4*)(wr + 24); w07 = *(const float4*)(wr + 28);
        w08 = *(const float4*)(wr + 32); w09 = *(const float4*)(wr + 36);
        w10 = *(const float4*)(wr + 40); w11 = *(const float4*)(wr + 44);
        if (p == 0) { w12 = *(const float4*)(wr + 48); b1 = bih1[h] + bhh1[h]; }
    } else if (l2t) {
        if (p3 == 0) {
            const float* wr = Wih2 + k2 * H1;           // [0..59]
            w00 = *(const float4*)(wr +  0); w01 = *(const float4*)(wr +  4);
            w02 = *(const float4*)(wr +  8); w03 = *(const float4*)(wr + 12);
            w04 = *(const float4*)(wr + 16); w05 = *(const float4*)(wr + 20);
            w06 = *(const float4*)(wr + 24); w07 = *(const float4*)(wr + 28);
            w08 = *(const float4*)(wr + 32); w09 = *(const float4*)(wr + 36);
            w10 = *(const float4*)(wr + 40); w11 = *(const float4*)(wr + 44);
            w12 = *(const float4*)(wr + 48); w13 = *(const float4*)(wr + 52);
            w14 = *(const float4*)(wr + 56);
            b2 = bih2[k2] + bhh2[k2];
        } else {
            const float* wr = Wih2 + k2 * H1 + 60;      // [60..99]
            w00 = *(const float4*)(wr +  0); w01 = *(const float4*)(wr +  4);
            w02 = *(const float4*)(wr +  8); w03 = *(const float4*)(wr + 12);
            w04 = *(const float4*)(wr + 16); w05 = *(const float4*)(wr + 20);
            w06 = *(const float4*)(wr + 24); w07 = *(const float4*)(wr + 28);
            w08 = *(const float4*)(wr + 32); w09 = *(const float4*)(wr + 36);
            const float* wh = Whh2 + k2 * H2;           // h2 part [100..119]
            w10 = *(const float4*)(wh +  0); w11 = *(const float4*)(wh +  4);
            w12 = *(const float4*)(wh +  8); w13 = *(const float4*)(wh + 12);
            w14 = *(const float4*)(wh + 16);
        }
    }

    for (int i = tid; i < 104; i += 320) { h1_s[0][i] = 0.f; h1_s[1][i] = 0.f; }
    for (int i = tid; i < 120; i += 320) { c_s[0][i] = 0.f; c_s[1][i] = 0.f; }

    // stage chunk 0 into buffer 0 (t = 0..7): one wide load per thread
    if (tid < 200) {
        const float4 mv = *(const float4*)&m1b[tid * 4];
        *(float4*)&m_lds[0][tid * 4] = mv;
    } else if (tid < 300) {
        const s16x8 pv = *(const s16x8*)&pTb[(tid - 200) * 8];
        float* dst = &p_lds[0][(tid - 200) * 8];
        *(float4*)dst       = make_float4(bf2f(pv[0]), bf2f(pv[1]), bf2f(pv[2]), bf2f(pv[3]));
        *(float4*)(dst + 4) = make_float4(bf2f(pv[4]), bf2f(pv[5]), bf2f(pv[6]), bf2f(pv[7]));
    }
    __syncthreads();

    int buf = 0;
    for (int c = 0; c < NCHK; ++c) {
        const bool more = (c + 1 < NCHK);
        float4 mst{}; s16x8 pst{};

        #pragma unroll
        for (int u = 0; u < CH; ++u) {
            const int t = c * CH + u;
            const int cur = t & 1, nxt = cur ^ 1;

            if (u > 0) STEP_BARRIER();         // LDS-only sync; no vmcnt drain

            if (u == 0 && more) {              // issue next chunk's loads
                const int base = (c + 1) * (CH * H1);
                if (tid < 200)      mst = *(const float4*)&m1b[base + tid * 4];
                else if (tid < 300) pst = *(const s16x8*)&pTb[base + (tid - 200) * 8];
            }

            if (l1t) {
                float a0 = (p == 0) ? (p_lds[buf][u * H1 + h] + b1) : 0.f;
                const float mv = (p == 1) ? m_lds[buf][u * H1 + h] : 0.f;
                float a1 = 0.f, a2 = 0.f, a3 = 0.f;
                const float* hb = &h1_s[cur][p * 52];
                FMA4(w00, hb +  0); FMA4(w01, hb +  4); FMA4(w02, hb +  8);
                FMA4(w03, hb + 12); FMA4(w04, hb + 16); FMA4(w05, hb + 20);
                FMA4(w06, hb + 24); FMA4(w07, hb + 28); FMA4(w08, hb + 32);
                FMA4(w09, hb + 36); FMA4(w10, hb + 40); FMA4(w11, hb + 44);
                FMA4(w12, hb + 48);
                float part = (a0 + a1) + (a2 + a3);
                float tot  = part + __shfl_xor(part, 1);
                tot = fmaxf(tot, 0.f);                       // h1(t)
                if (p == 0) h1_s[nxt][h] = tot;
                else        c_s[nxt][h] = tot * mv;          // o1(t)
            }

            if (l2t && t >= 1) {
                float a0 = (p3 == 0) ? b2 : 0.f;
                float a1 = 0.f, a2 = 0.f, a3 = 0.f;
                const float* cb = &c_s[cur][p3 * 60];
                FMA4(w00, cb +  0); FMA4(w01, cb +  4); FMA4(w02, cb +  8);
                FMA4(w03, cb + 12); FMA4(w04, cb + 16); FMA4(w05, cb + 20);
                FMA4(w06, cb + 24); FMA4(w07, cb + 28); FMA4(w08, cb + 32);
                FMA4(w09, cb + 36); FMA4(w10, cb + 40); FMA4(w11, cb + 44);
                FMA4(w12, cb + 48); FMA4(w13, cb + 52); FMA4(w14, cb + 56);
                float part = (a0 + a1) + (a2 + a3);
                part += __shfl_xor(part, 1);
                const float h2v = fmaxf(part, 0.f);          // h2(t-1)
                if (p3 == 0) c_s[nxt][100 + k2] = h2v;
            }
        }

        if (more) {                            // publish staged chunk
            if (tid < 200) {
                *(float4*)&m_lds[buf ^ 1][tid * 4] = mst;
            } else if (tid < 300) {
                float* dst = &p_lds[buf ^ 1][(tid - 200) * 8];
                *(float4*)dst       = make_float4(bf2f(pst[0]), bf2f(pst[1]), bf2f(pst[2]), bf2f(pst[3]));
                *(float4*)(dst + 4) = make_float4(bf2f(pst[4]), bf2f(pst[5]), bf2f(pst[6]), bf2f(pst[7]));
            }
            buf ^= 1;
        }
        __syncthreads();                        // chunk boundary: full fence
    }

    // epilogue t = TT: layer2 computes h2(199) from o1(199), h2(198)
    {
        const int cur = TT & 1;                              // 0
        if (l2t) {
            float a0 = (p3 == 0) ? b2 : 0.f;
            float a1 = 0.f, a2 = 0.f, a3 = 0.f;
            const float* cb = &c_s[cur][p3 * 60];
            FMA4(w00, cb +  0); FMA4(w01, cb +  4); FMA4(w02, cb +  8);
            FMA4(w03, cb + 12); FMA4(w04, cb + 16); FMA4(w05, cb + 20);
            FMA4(w06, cb + 24); FMA4(w07, cb + 28); FMA4(w08, cb + 32);
            FMA4(w09, cb + 36); FMA4(w10, cb + 40); FMA4(w11, cb + 44);
            FMA4(w12, cb + 48); FMA4(w13, cb + 52); FMA4(w14, cb + 56);
            float part = (a0 + a1) + (a2 + a3);
            part += __shfl_xor(part, 1);
            if (p3 == 0) h2f_s[k2] = fmaxf(part, 0.f);       // h2(199)
        }
        __syncthreads();
    }

    if (tid < NO) {
        const float* m2 = mask2 + ((size_t)b * TT + (TT - 1)) * H2;
        float s = bfc[tid];
        #pragma unroll
        for (int k = 0; k < H2; ++k)
            s = fmaf(Wfc[tid * H2 + k], h2f_s[k] * m2[k], s);
        out[b * NO + tid] = s;
    }
}

extern "C" void kernel_launch(void* const* d_in, const int* in_sizes, int n_in,
                              void* d_out, int out_size, void* d_ws, size_t ws_size,
                              hipStream_t stream) {
    const float* x     = (const float*)d_in[0];
    const float* Wih1  = (const float*)d_in[1];
    const float* Whh1  = (const float*)d_in[2];
    const float* bih1  = (const float*)d_in[3];
    const float* bhh1  = (const float*)d_in[4];
    const float* Wih2  = (const float*)d_in[5];
    const float* Whh2  = (const float*)d_in[6];
    const float* bih2  = (const float*)d_in[7];
    const float* bhh2  = (const float*)d_in[8];
    const float* Wfc   = (const float*)d_in[9];
    const float* bfc   = (const float*)d_in[10];
    const float* mask1 = (const float*)d_in[11];
    const float* mask2 = (const float*)d_in[12];
    float* out = (float*)d_out;

    unsigned short* preT = (unsigned short*)d_ws;                     // 10,240,000 B
    unsigned short* w_ws = (unsigned short*)((char*)d_ws + 10240000); //    286,720 B

    prep_w  <<<dim3((WR * KPAD / 4 + 255) / 256), dim3(256), 0, stream>>>(Wih1, w_ws);
    gemm_pre<<<dim3(GRID_A), dim3(256), 0, stream>>>(x, w_ws, preT);
    scan_rnn<<<dim3(NB), dim3(320), 0, stream>>>(preT, Whh1, bih1, bhh1,
                                                 Wih2, Whh2, bih2, bhh2,
                                                 Wfc, bfc, mask1, mask2, out);
}